// Round 2
// baseline (117.974 us; speedup 1.0000x reference)
//
#include <hip/hip_runtime.h>
#include <math.h>

// Problem constants (from reference)
#define BB 4
#define TT 1024
#define DD 1024
#define VV 32000
#define WW 8

// One block per (b, t) row: compute gate = sigmoid(dot(hidden[row], gate_w) + b),
// softmax lag weights, then thread 0 dedup-accumulates <=8 lagged-token
// contributions and stores them into the (already memset-zeroed) output row.
__global__ __launch_bounds__(256) void recent_copy_scatter_kernel(
    const float* __restrict__ hidden,      // (B,T,D) f32
    const int*   __restrict__ input_ids,   // (B,T)   int32
    const float* __restrict__ gate_w,      // (D,1)   f32
    const float* __restrict__ gate_b,      // (1,)    f32
    const float* __restrict__ lag_logits,  // (W,)    f32
    const float* __restrict__ copy_scale,  // (1,)    f32
    float*       __restrict__ out)         // (B,T,V) f32, pre-zeroed
{
    const int row = blockIdx.x;            // 0 .. B*T-1
    const int b   = row / TT;
    const int p   = row % TT;
    const int tid = threadIdx.x;

    // ---- dot(hidden[row,:], gate_w[:,0]) : each thread one float4 ----
    const float4* h4 = reinterpret_cast<const float4*>(hidden + (size_t)row * DD);
    const float4* w4 = reinterpret_cast<const float4*>(gate_w);
    float4 hv = h4[tid];       // DD/4 == 256 == blockDim.x
    float4 wv = w4[tid];
    float s = hv.x * wv.x + hv.y * wv.y + hv.z * wv.z + hv.w * wv.w;

    // wave(64) butterfly reduce
    #pragma unroll
    for (int off = 32; off > 0; off >>= 1)
        s += __shfl_down(s, off, 64);

    __shared__ float partial[4];
    const int wave = tid >> 6;
    const int lane = tid & 63;
    if (lane == 0) partial[wave] = s;
    __syncthreads();

    // ---- scatter (single thread; <=8 entries, dedup deterministic) ----
    if (tid == 0) {
        float dot = partial[0] + partial[1] + partial[2] + partial[3];
        float gate = 1.0f / (1.0f + __expf(-(dot + gate_b[0])));

        // softmax over 8 lag logits
        float lw[WW];
        float m = -1e30f;
        #pragma unroll
        for (int i = 0; i < WW; ++i) { lw[i] = lag_logits[i]; m = fmaxf(m, lw[i]); }
        float sum = 0.f;
        #pragma unroll
        for (int i = 0; i < WW; ++i) { lw[i] = __expf(lw[i] - m); sum += lw[i]; }
        const float scale = copy_scale[0] * gate / sum;

        const int nl = (p + 1 < WW) ? (p + 1) : WW;   // valid lags: p >= lag
        int   toks[WW];
        float contrib[WW];
        for (int l = 0; l < nl; ++l) {
            toks[l]    = input_ids[b * TT + p - l];
            contrib[l] = scale * lw[l];
        }

        float* orow = out + (size_t)row * VV;
        for (int i = 0; i < nl; ++i) {
            bool first = true;
            for (int j = 0; j < i; ++j)
                if (toks[j] == toks[i]) { first = false; break; }
            if (!first) continue;
            float tot = contrib[i];
            for (int j = i + 1; j < nl; ++j)
                if (toks[j] == toks[i]) tot += contrib[j];
            orow[toks[i]] = tot;
        }
    }
}

extern "C" void kernel_launch(void* const* d_in, const int* in_sizes, int n_in,
                              void* d_out, int out_size, void* d_ws, size_t ws_size,
                              hipStream_t stream) {
    (void)in_sizes; (void)n_in; (void)d_ws; (void)ws_size;

    const float* hidden     = (const float*)d_in[0];
    const int*   input_ids  = (const int*)  d_in[1];
    const float* gate_w     = (const float*)d_in[2];
    const float* gate_b     = (const float*)d_in[3];
    const float* lag_logits = (const float*)d_in[4];
    const float* copy_scale = (const float*)d_in[5];
    float* out = (float*)d_out;

    // 1. Bulk zero-fill on the AMD-optimized fill path (~7 TB/s measured).
    hipMemsetAsync(d_out, 0, (size_t)out_size * sizeof(float), stream);

    // 2. Tiny scatter kernel: gate dot-product + <=8 scattered stores per row.
    dim3 grid(BB * TT);   // 4096 blocks, one per (b,t) row
    dim3 block(256);
    recent_copy_scatter_kernel<<<grid, block, 0, stream>>>(
        hidden, input_ids, gate_w, gate_b, lag_logits, copy_scale, out);
}

// Round 4
// 110.700 us; speedup vs baseline: 1.0657x; 1.0657x over previous
//
#include <hip/hip_runtime.h>
#include <math.h>

// Problem constants (from reference)
#define BB 4
#define TT 1024
#define DD 1024
#define VV 32000
#define WW 8

typedef float vfloat4 __attribute__((ext_vector_type(4)));  // native clang vec for nt-store

// One fused kernel, one block per (b, t) row:
//  - dot(hidden[row], gate_w) via float4 loads + wave/LDS reduce
//  - zero the 32000-float output row with NON-TEMPORAL float4 stores
//    (bypass L2/LLC write-allocate: the row is written once, never read)
//  - thread 0: sigmoid gate, 8-way softmax, dedup-accumulate <=8 lagged-token
//    contributions, normal stores into the zeroed row (after __syncthreads,
//    which drains vmcnt so the nt zeros are complete first).
__global__ __launch_bounds__(256) void recent_copy_bias_kernel(
    const float* __restrict__ hidden,      // (B,T,D) f32
    const int*   __restrict__ input_ids,   // (B,T)   int32
    const float* __restrict__ gate_w,      // (D,1)   f32
    const float* __restrict__ gate_b,      // (1,)    f32
    const float* __restrict__ lag_logits,  // (W,)    f32
    const float* __restrict__ copy_scale,  // (1,)    f32
    float*       __restrict__ out)         // (B,T,V) f32
{
    const int row = blockIdx.x;            // 0 .. B*T-1
    const int b   = row / TT;
    const int p   = row % TT;
    const int tid = threadIdx.x;

    // ---- 1. dot(hidden[row,:], gate_w[:,0]) : each thread one float4 ----
    const float4* h4 = reinterpret_cast<const float4*>(hidden + (size_t)row * DD);
    const float4* w4 = reinterpret_cast<const float4*>(gate_w);
    float4 hv = h4[tid];       // DD/4 == 256 == blockDim.x
    float4 wv = w4[tid];
    float s = hv.x * wv.x + hv.y * wv.y + hv.z * wv.z + hv.w * wv.w;

    // wave(64) butterfly reduce
    #pragma unroll
    for (int off = 32; off > 0; off >>= 1)
        s += __shfl_down(s, off, 64);

    __shared__ float partial[4];
    const int wave = tid >> 6;
    const int lane = tid & 63;
    if (lane == 0) partial[wave] = s;

    // ---- 2. zero this output row: non-temporal, coalesced 16B stores ----
    vfloat4* orow4 = reinterpret_cast<vfloat4*>(out + (size_t)row * VV);
    const vfloat4 z4 = {0.f, 0.f, 0.f, 0.f};
    #pragma unroll 4
    for (int i = tid; i < VV / 4; i += 256)          // VV/4 = 8000 per row
        __builtin_nontemporal_store(z4, &orow4[i]);

    __syncthreads();   // exec barrier + vmcnt drain: zeros complete, partials visible

    // ---- 3. scatter (single thread; <=8 entries, dedup deterministic) ----
    if (tid == 0) {
        float dot = partial[0] + partial[1] + partial[2] + partial[3];
        float gate = 1.0f / (1.0f + __expf(-(dot + gate_b[0])));

        // softmax over 8 lag logits
        float lw[WW];
        float m = -1e30f;
        #pragma unroll
        for (int i = 0; i < WW; ++i) { lw[i] = lag_logits[i]; m = fmaxf(m, lw[i]); }
        float sum = 0.f;
        #pragma unroll
        for (int i = 0; i < WW; ++i) { lw[i] = __expf(lw[i] - m); sum += lw[i]; }
        const float scale = copy_scale[0] * gate / sum;

        const int nl = (p + 1 < WW) ? (p + 1) : WW;   // valid lags: p >= lag
        int   toks[WW];
        float contrib[WW];
        for (int l = 0; l < nl; ++l) {
            toks[l]    = input_ids[b * TT + p - l];
            contrib[l] = scale * lw[l];
        }

        float* orow = out + (size_t)row * VV;
        for (int i = 0; i < nl; ++i) {
            bool first = true;
            for (int j = 0; j < i; ++j)
                if (toks[j] == toks[i]) { first = false; break; }
            if (!first) continue;
            float tot = contrib[i];
            for (int j = i + 1; j < nl; ++j)
                if (toks[j] == toks[i]) tot += contrib[j];
            orow[toks[i]] = tot;
        }
    }
}

extern "C" void kernel_launch(void* const* d_in, const int* in_sizes, int n_in,
                              void* d_out, int out_size, void* d_ws, size_t ws_size,
                              hipStream_t stream) {
    (void)in_sizes; (void)n_in; (void)d_ws; (void)ws_size;

    const float* hidden     = (const float*)d_in[0];
    const int*   input_ids  = (const int*)  d_in[1];
    const float* gate_w     = (const float*)d_in[2];
    const float* gate_b     = (const float*)d_in[3];
    const float* lag_logits = (const float*)d_in[4];
    const float* copy_scale = (const float*)d_in[5];
    float* out = (float*)d_out;

    dim3 grid(BB * TT);   // 4096 blocks, one per (b,t) row
    dim3 block(256);
    recent_copy_bias_kernel<<<grid, block, 0, stream>>>(
        hidden, input_ids, gate_w, gate_b, lag_logits, copy_scale, out);
}

// Round 5
// 109.197 us; speedup vs baseline: 1.0804x; 1.0138x over previous
//
#include <hip/hip_runtime.h>
#include <math.h>

// Problem constants (from reference)
#define BB 4
#define TT 1024
#define DD 1024
#define VV 32000
#define WW 8

typedef float vfloat4 __attribute__((ext_vector_type(4)));

// One WAVE per (b,t) row. No LDS, no __syncthreads, no block coupling.
//  - dot(hidden[row], gate_w): 16 floats/lane (4x float4), shfl_xor reduce
//  - all lanes compute gate/softmax/dedup'd (tok, contrib) list in registers
//  - tight pure non-temporal zero-store stream (125 float4/lane)
//  - per-wave vmcnt(0) drain, then lane 0 stores the <=8 scatter dwords
__global__ __launch_bounds__(256) void recent_copy_bias_kernel(
    const float* __restrict__ hidden,      // (B,T,D) f32
    const int*   __restrict__ input_ids,   // (B,T)   int32
    const float* __restrict__ gate_w,      // (D,1)   f32
    const float* __restrict__ gate_b,      // (1,)    f32
    const float* __restrict__ lag_logits,  // (W,)    f32
    const float* __restrict__ copy_scale,  // (1,)    f32
    float*       __restrict__ out)         // (B,T,V) f32
{
    const int tid  = threadIdx.x;
    const int wid  = tid >> 6;
    const int lane = tid & 63;
    const int row  = blockIdx.x * 4 + wid;   // grid = 1024 -> 4096 rows
    const int b    = row >> 10;              // TT = 1024
    const int p    = row & (TT - 1);

    // ---- 1. dot(hidden[row,:], gate_w[:,0]): 16 consecutive floats per lane ----
    const float4* h4 = reinterpret_cast<const float4*>(hidden + (size_t)row * DD) + lane * 4;
    const float4* w4 = reinterpret_cast<const float4*>(gate_w) + lane * 4;
    float s = 0.f;
    #pragma unroll
    for (int k = 0; k < 4; ++k) {
        float4 a = h4[k], w = w4[k];
        s += a.x * w.x + a.y * w.y + a.z * w.z + a.w * w.w;
    }
    #pragma unroll
    for (int off = 32; off > 0; off >>= 1)
        s += __shfl_xor(s, off, 64);
    // s now holds the full dot in every lane

    // ---- 2. gate, softmax(lag_logits), (tok, contrib) list — all lanes ----
    const float gate = 1.0f / (1.0f + __expf(-(s + gate_b[0])));

    float lw[WW];
    float m = -1e30f;
    #pragma unroll
    for (int i = 0; i < WW; ++i) { lw[i] = lag_logits[i]; m = fmaxf(m, lw[i]); }
    float sum = 0.f;
    #pragma unroll
    for (int i = 0; i < WW; ++i) { lw[i] = __expf(lw[i] - m); sum += lw[i]; }
    const float scale = copy_scale[0] * gate / sum;

    // valid lag l iff p >= l. Invalid entries get a unique negative token
    // (never merges, never stored) and zero contribution. All static indices.
    int   toks[WW];
    float contrib[WW];
    #pragma unroll
    for (int l = 0; l < WW; ++l) {
        const bool valid = (p >= l);
        const int  idx   = b * TT + (valid ? (p - l) : 0);
        toks[l]    = valid ? input_ids[idx] : (-1 - l);
        contrib[l] = valid ? (scale * lw[l]) : 0.f;
    }

    // ---- 3. pure non-temporal zero-store stream: 8000/64 = 125 iters/lane ----
    vfloat4* orow4 = reinterpret_cast<vfloat4*>(out + (size_t)row * VV);
    const vfloat4 z4 = {0.f, 0.f, 0.f, 0.f};
    #pragma unroll 5
    for (int i = lane; i < VV / 4; i += 64)
        __builtin_nontemporal_store(z4, &orow4[i]);

    // ---- 4. per-wave drain: zeros committed before the scatter fix-ups ----
    asm volatile("s_waitcnt vmcnt(0)" ::: "memory");

    // ---- 5. lane 0 stores the dedup'd scatter values (<=8 dwords) ----
    if (lane == 0) {
        float* orow = out + (size_t)row * VV;
        #pragma unroll
        for (int i = 0; i < WW; ++i) {
            if (toks[i] < 0) continue;
            bool first = true;
            #pragma unroll
            for (int j = 0; j < WW; ++j)
                if (j < i && toks[j] == toks[i]) first = false;
            if (!first) continue;
            float tot = contrib[i];
            #pragma unroll
            for (int j = 0; j < WW; ++j)
                if (j > i && toks[j] == toks[i]) tot += contrib[j];
            orow[toks[i]] = tot;
        }
    }
}

extern "C" void kernel_launch(void* const* d_in, const int* in_sizes, int n_in,
                              void* d_out, int out_size, void* d_ws, size_t ws_size,
                              hipStream_t stream) {
    (void)in_sizes; (void)n_in; (void)d_ws; (void)ws_size;

    const float* hidden     = (const float*)d_in[0];
    const int*   input_ids  = (const int*)  d_in[1];
    const float* gate_w     = (const float*)d_in[2];
    const float* gate_b     = (const float*)d_in[3];
    const float* lag_logits = (const float*)d_in[4];
    const float* copy_scale = (const float*)d_in[5];
    float* out = (float*)d_out;

    dim3 grid(BB * TT / 4);   // 1024 blocks, 4 waves/block, one wave per row
    dim3 block(256);
    recent_copy_bias_kernel<<<grid, block, 0, stream>>>(
        hidden, input_ids, gate_w, gate_b, lag_logits, copy_scale, out);
}

// Round 6
// 105.842 us; speedup vs baseline: 1.1146x; 1.0317x over previous
//
#include <hip/hip_runtime.h>
#include <math.h>

// Problem constants (from reference)
#define BB 4
#define TT 1024
#define DD 1024
#define VV 32000
#define WW 8
#define CHUNKS (VV / 4)    // 8000 float4 chunks per row
#define QCH (CHUNKS / 4)   // 2000 chunks per wave (quarter row)

typedef float vfloat4 __attribute__((ext_vector_type(4)));

// One BLOCK per row, one WAVE per quarter-row. Single output pass:
//  - every wave redundantly computes gate (4KB row read, L1/TCC-merged),
//    softmax, dedup'd (token -> value) list — all in registers, no LDS
//  - wave sweeps its 2000-chunk quarter with NT stores, injecting the
//    token values via cndmask on the matching chunk (no RMW, no drain,
//    no scatter tail, no barriers)
__global__ __launch_bounds__(256) void recent_copy_bias_kernel(
    const float* __restrict__ hidden,      // (B,T,D) f32
    const int*   __restrict__ input_ids,   // (B,T)   int32
    const float* __restrict__ gate_w,      // (D,1)   f32
    const float* __restrict__ gate_b,      // (1,)    f32
    const float* __restrict__ lag_logits,  // (W,)    f32
    const float* __restrict__ copy_scale,  // (1,)    f32
    float*       __restrict__ out)         // (B,T,V) f32
{
    const int tid  = threadIdx.x;
    const int wid  = tid >> 6;
    const int lane = tid & 63;
    const int row  = blockIdx.x;           // 4096 blocks, one per (b,t) row
    const int b    = row >> 10;            // TT = 1024
    const int p    = row & (TT - 1);

    // ---- 1. dot(hidden[row,:], gate_w): 16 floats/lane, shfl_xor reduce ----
    const float4* h4 = reinterpret_cast<const float4*>(hidden + (size_t)row * DD) + lane * 4;
    const float4* w4 = reinterpret_cast<const float4*>(gate_w) + lane * 4;
    float s = 0.f;
    #pragma unroll
    for (int k = 0; k < 4; ++k) {
        float4 a = h4[k], w = w4[k];
        s += a.x * w.x + a.y * w.y + a.z * w.z + a.w * w.w;
    }
    #pragma unroll
    for (int off = 32; off > 0; off >>= 1)
        s += __shfl_xor(s, off, 64);

    // ---- 2. gate, softmax, dedup'd token list (all lanes, registers) ----
    const float gate = 1.0f / (1.0f + __expf(-(s + gate_b[0])));

    float lw[WW];
    float m = -1e30f;
    #pragma unroll
    for (int i = 0; i < WW; ++i) { lw[i] = lag_logits[i]; m = fmaxf(m, lw[i]); }
    float sum = 0.f;
    #pragma unroll
    for (int i = 0; i < WW; ++i) { lw[i] = __expf(lw[i] - m); sum += lw[i]; }
    const float scale = copy_scale[0] * gate / sum;

    int   toks[WW];
    float contrib[WW];
    #pragma unroll
    for (int l = 0; l < WW; ++l) {
        const bool valid = (p >= l);
        toks[l]    = valid ? input_ids[b * TT + (valid ? (p - l) : 0)] : -1;
        contrib[l] = valid ? (scale * lw[l]) : 0.f;
    }

    // Dedup (first occurrence accumulates duplicates) + filter to my quarter.
    // Static indexing only (runtime-indexed arrays go to scratch).
    const int qlo = wid * QCH;             // first chunk of my quarter
    int   lc[WW];                          // chunk-local index, or -1 (dead)
    int   lcomp[WW];
    float lval[WW];
    #pragma unroll
    for (int i = 0; i < WW; ++i) {
        bool keep = (toks[i] >= 0);
        #pragma unroll
        for (int j = 0; j < WW; ++j)
            if (j < i && toks[j] == toks[i]) keep = false;
        float tot = contrib[i];
        #pragma unroll
        for (int j = 0; j < WW; ++j)
            if (j > i && toks[j] == toks[i]) tot += contrib[j];
        const int ch = toks[i] >> 2;       // -1 for dead slots
        keep = keep && (ch >= qlo) && (ch < qlo + QCH);
        lc[i]    = keep ? (ch - qlo) : -1;
        lcomp[i] = toks[i] & 3;
        lval[i]  = tot;
    }

    // ---- 3. single-pass quarter-row sweep: NT stores with value inject ----
    vfloat4* qbase = reinterpret_cast<vfloat4*>(out + (size_t)row * VV) + qlo;

    #pragma unroll 4
    for (int i = 0; i < QCH / 64; ++i) {   // 31 full iterations
        const int c = i * 64 + lane;
        vfloat4 v = {0.f, 0.f, 0.f, 0.f};
        #pragma unroll
        for (int t = 0; t < WW; ++t) {
            const bool hit = (lc[t] == c);
            v.x = (hit && lcomp[t] == 0) ? lval[t] : v.x;
            v.y = (hit && lcomp[t] == 1) ? lval[t] : v.y;
            v.z = (hit && lcomp[t] == 2) ? lval[t] : v.z;
            v.w = (hit && lcomp[t] == 3) ? lval[t] : v.w;
        }
        __builtin_nontemporal_store(v, &qbase[c]);
    }
    // tail: chunks 1984..1999 (lanes 0..15)
    {
        const int c = (QCH / 64) * 64 + lane;
        if (c < QCH) {
            vfloat4 v = {0.f, 0.f, 0.f, 0.f};
            #pragma unroll
            for (int t = 0; t < WW; ++t) {
                const bool hit = (lc[t] == c);
                v.x = (hit && lcomp[t] == 0) ? lval[t] : v.x;
                v.y = (hit && lcomp[t] == 1) ? lval[t] : v.y;
                v.z = (hit && lcomp[t] == 2) ? lval[t] : v.z;
                v.w = (hit && lcomp[t] == 3) ? lval[t] : v.w;
            }
            __builtin_nontemporal_store(v, &qbase[c]);
        }
    }
}

extern "C" void kernel_launch(void* const* d_in, const int* in_sizes, int n_in,
                              void* d_out, int out_size, void* d_ws, size_t ws_size,
                              hipStream_t stream) {
    (void)in_sizes; (void)n_in; (void)d_ws; (void)ws_size;

    const float* hidden     = (const float*)d_in[0];
    const int*   input_ids  = (const int*)  d_in[1];
    const float* gate_w     = (const float*)d_in[2];
    const float* gate_b     = (const float*)d_in[3];
    const float* lag_logits = (const float*)d_in[4];
    const float* copy_scale = (const float*)d_in[5];
    float* out = (float*)d_out;

    dim3 grid(BB * TT);   // one block per row; 4 waves = 4 quarter-rows
    dim3 block(256);
    recent_copy_bias_kernel<<<grid, block, 0, stream>>>(
        hidden, input_ids, gate_w, gate_b, lag_logits, copy_scale, out);
}